// Round 9
// baseline (61.576 us; speedup 1.0000x reference)
//
#include <hip/hip_runtime.h>
#include <hip/hip_bf16.h>

// DivEncLayer via MFMA + global_load_lds staging, R9.
// per (b,q): z = W1^T x + b1; out = sum_h w2p*elu(z) + b2p.  B=32768, Q=128, S=8, H=32.
//
// R8 -> R9 (counter-driven): true per-wave regs (arch 52 + accum/cini ~64 on the unified
// file) capped residency at 4 waves/SIMD in R6 AND R8 (both measured ~36% Occ); per-wave
// MLP was ~4 loads -> Little's law gives exactly the measured ~1 TB/s. Fix: stage x via
// __builtin_amdgcn_global_load_lds into double-buffered LDS (in-flight bytes cost 0 VGPR),
// XOR-swizzled global source (LDS linear, G21) so ds_read_b128 is bank-conflict-free.
// Block = 8 waves x 128 rows x 16 q; chunk = 32 rows (16KB); single 32x32x16 MFMA per q
// (A k8-15 = 0 -> B hi-lanes are don't-care; bias enters via C=b1). LDS 35KB -> 4 blk/CU.

#define QN 128
#define SN 8
#define HN 32
#define XROW 1024
#define BN_EPS 1e-3f
#define ROWS_BLK 128
#define QBLK 16

typedef short bf16x8 __attribute__((ext_vector_type(8)));
typedef float f32x16 __attribute__((ext_vector_type(16)));
typedef unsigned int u32;

typedef __attribute__((address_space(1))) void as1_void;
typedef __attribute__((address_space(3))) void as3_void;

#define WS_A_BYTES (QN * 64 * 16)                 // A[q][lane] 16B (lanes>=32 zero)
#define WS_C_OFF   WS_A_BYTES
#define WS_C_BYTES (QN * 32 * 4)                  // c_init[q][half*16+r] = b1 (f32, reg order)
#define WS_W_OFF   (WS_C_OFF + WS_C_BYTES)
#define WS_W_BYTES (QN * 32 * 4)                  // w2p[q][half*16+r]
#define WS_B2_OFF  (WS_W_OFF + WS_W_BYTES)        // b2p[q]

static __device__ __forceinline__ u32 pkbf(float lo, float hi) {
    union { __hip_bfloat162 h2; u32 u; } c;
    c.h2 = __float22bfloat162_rn(float2{lo, hi});
    return c.u;
}

__global__ void divenc_prep(const float* __restrict__ W1, const float* __restrict__ b1,
                            const float* __restrict__ gamma_, const float* __restrict__ beta_,
                            const float* __restrict__ mmean, const float* __restrict__ mvar,
                            const float* __restrict__ W2, const float* __restrict__ b2,
                            unsigned char* __restrict__ ws)
{
    const int q = blockIdx.x;        // 0..127
    const int m = threadIdx.x;       // 0..63

    u32 d0 = 0, d1 = 0, d2 = 0, d3 = 0;
    if (m < 32) {                    // A[m][k] = W1[q][k][m], k pairs per dword
        d0 = pkbf(W1[(q*SN + 0)*HN + m], W1[(q*SN + 1)*HN + m]);
        d1 = pkbf(W1[(q*SN + 2)*HN + m], W1[(q*SN + 3)*HN + m]);
        d2 = pkbf(W1[(q*SN + 4)*HN + m], W1[(q*SN + 5)*HN + m]);
        d3 = pkbf(W1[(q*SN + 6)*HN + m], W1[(q*SN + 7)*HN + m]);
    }
    ((uint4*)ws)[q*64 + m] = uint4{d0, d1, d2, d3};

    float* wsC  = (float*)(ws + WS_C_OFF);
    float* wsW  = (float*)(ws + WS_W_OFF);
    float* wsB2 = (float*)(ws + WS_B2_OFF);
    if (m < 32) {                    // D-reg order: h = (r&3) + 8*(r>>2) + 4*half
        const int half = m >> 4, r = m & 15;
        const int h = (r & 3) + 8*(r >> 2) + 4*half;
        wsC[q*32 + m] = b1[q*HN + h];
        float inv = gamma_[q*HN+h] * rsqrtf(mvar[q*HN+h] + BN_EPS);
        wsW[q*32 + m] = inv * W2[q*HN + h];
    }
    if (m == 0) {
        float acc = b2[q];
        for (int h = 0; h < HN; ++h) {
            float inv = gamma_[q*HN+h] * rsqrtf(mvar[q*HN+h] + BN_EPS);
            acc += (beta_[q*HN+h] - mmean[q*HN+h]*inv) * W2[q*HN+h];
        }
        wsB2[q] = acc;
    }
}

// Stage one 32-row chunk (16 KB) into LDS. 16 instrs of 1KB; wave wv issues 2.
// Instr i covers chunk rows {2i, 2i+1}: lanes 0-31 -> row 2i, lanes 32-63 -> row 2i+1.
// XOR swizzle on the GLOBAL source: phys 16B-slot (lane&31) receives logical block
// (lane&31)^row, so the LDS dest stays linear (global_load_lds requirement).
__device__ __forceinline__
void stage_chunk(const float* __restrict__ x, u32* lds_base,
                 int b0, int q0, int c, int wv, int lane)
{
    #pragma unroll
    for (int k = 0; k < 2; ++k) {
        const int i  = wv * 2 + k;               // 0..15
        const int r  = i * 2 + (lane >> 5);      // chunk-local row 0..31
        const int jl = (lane & 31) ^ r;          // logical 16B-block index
        const float* src = x + (size_t)(b0 + c * 32 + r) * XROW + q0 * SN + jl * 4;
        u32* dst = lds_base + i * 256;           // wave-uniform; HW adds lane*16B
        __builtin_amdgcn_global_load_lds((const as1_void*)src, (as3_void*)dst, 16, 0, 0);
    }
}

__global__ __launch_bounds__(512, 4)
void divenc_mfma(const float* __restrict__ x, const unsigned char* __restrict__ ws,
                 float* __restrict__ out)
{
    const int lane = threadIdx.x & 63;
    const int wv   = threadIdx.x >> 6;   // 0..7
    const int half = lane >> 5;
    const int rr   = lane & 31;          // this lane's b-row within the chunk
    const int b0   = blockIdx.x * ROWS_BLK;
    const int q0   = blockIdx.y * QBLK;

    const uint4* wsA  = (const uint4*)ws;
    const float* wsC  = (const float*)(ws + WS_C_OFF);
    const float* wsW  = (const float*)(ws + WS_W_OFF);
    const float* wsB2 = (const float*)(ws + WS_B2_OFF);

    __shared__ u32   xbuf[2][32 * 128];  // 2 x 16 KiB (32 rows x 512B, swizzled blocks)
    __shared__ float slab[32][17];       // chunk output; stride 17 = conflict-free

    stage_chunk(x, xbuf[0], b0, q0, 0, wv, lane);

    #pragma unroll 1
    for (int c = 0; c < 4; ++c) {
        __syncthreads();                 // stage(c) complete (vmcnt drained); slab free

        if (c < 3) stage_chunk(x, xbuf[(c + 1) & 1], b0, q0, c + 1, wv, lane);

        const u32* xb = xbuf[c & 1];
        #pragma unroll
        for (int qg = 0; qg < 2; ++qg) {
            const int ql = qg * 8 + wv;          // 0..15
            const int q  = q0 + ql;

            union { uint4 u; bf16x8 v; } A;
            A.u = wsA[q * 64 + lane];

            f32x16 cini;
            const float* cp_ = wsC + q * 32 + half * 16;
            #pragma unroll
            for (int r = 0; r < 16; ++r) cini[r] = cp_[r];
            float w2r[16];
            const float* wp_ = wsW + q * 32 + half * 16;
            #pragma unroll
            for (int r = 0; r < 16; ++r) w2r[r] = wp_[r];
            const float b2p = wsB2[q];

            // lane's row rr, logical blocks 2ql/2ql+1 -> phys = logical ^ rr
            const u32* rowp = xb + rr * 128;
            const uint4 xw0 = *(const uint4*)(rowp + ((2 * ql)     ^ rr) * 4);
            const uint4 xw1 = *(const uint4*)(rowp + ((2 * ql + 1) ^ rr) * 4);

            union { uint4 u; bf16x8 v; } B;
            B.u = uint4{ pkbf(__uint_as_float(xw0.x), __uint_as_float(xw0.y)),
                         pkbf(__uint_as_float(xw0.z), __uint_as_float(xw0.w)),
                         pkbf(__uint_as_float(xw1.x), __uint_as_float(xw1.y)),
                         pkbf(__uint_as_float(xw1.z), __uint_as_float(xw1.w)) };

            // A lanes>=32 are zero => B hi-lane values are don't-care (finite x dups).
            f32x16 D = __builtin_amdgcn_mfma_f32_32x32x16_bf16(A.v, B.v, cini, 0, 0, 0);

            float p = 0.f;
            #pragma unroll
            for (int r = 0; r < 16; ++r) {
                float z = D[r];
                float e = __expf(fminf(z, 0.f)) - 1.f;   // z>0 -> e=0
                p = fmaf(fmaxf(z, e), w2r[r], p);        // exact ELU * w2p
            }
            p += __shfl_xor(p, 32);                       // combine the two h-halves
            if (half == 0) slab[rr][ql] = p + b2p;
        }

        __syncthreads();                 // slab complete (stage(c+1) had full compute to land)

        if (threadIdx.x < 128) {         // dump 32 rows x 16 q, float4 per thread
            const int row = threadIdx.x >> 2;
            const int c4  = (threadIdx.x & 3) * 4;
            float4 vv;
            vv.x = slab[row][c4 + 0];
            vv.y = slab[row][c4 + 1];
            vv.z = slab[row][c4 + 2];
            vv.w = slab[row][c4 + 3];
            *(float4*)(out + (size_t)(b0 + c * 32 + row) * QN + q0 + c4) = vv;
        }
    }
}

extern "C" void kernel_launch(void* const* d_in, const int* in_sizes, int n_in,
                              void* d_out, int out_size, void* d_ws, size_t ws_size,
                              hipStream_t stream) {
    const float* x      = (const float*)d_in[0];
    const float* W1     = (const float*)d_in[1];
    const float* b1     = (const float*)d_in[2];
    const float* gamma_ = (const float*)d_in[3];
    const float* beta_  = (const float*)d_in[4];
    const float* mmean  = (const float*)d_in[5];
    const float* mvar   = (const float*)d_in[6];
    const float* W2     = (const float*)d_in[7];
    const float* b2     = (const float*)d_in[8];
    float* out = (float*)d_out;
    unsigned char* ws = (unsigned char*)d_ws;

    const int Btot = in_sizes[0] / XROW;              // 32768

    divenc_prep<<<QN, 64, 0, stream>>>(W1, b1, gamma_, beta_, mmean, mvar, W2, b2, ws);
    divenc_mfma<<<dim3(Btot / ROWS_BLK, QN / QBLK), 512, 0, stream>>>(x, ws, out);
}

// Round 10
// 55.579 us; speedup vs baseline: 1.1079x; 1.1079x over previous
//
#include <hip/hip_runtime.h>
#include <hip/hip_bf16.h>

// DivEncLayer via MFMA, R10: minimize unified VGPR+AGPR to lift wave residency.
// per (b,q): z = W1^T x + b1; out = sum_h w2p*elu(z) + b2p.  B=32768, Q=128, S=8, H=32.
//
// R9 -> R10: R6/R8/R9 all pinned at Occ~37% / VALUBusy~38% -- residency capped at
// 4 waves/SIMD by unified VGPR+AGPR (~120: dual-MFMA 32 AGPR + cini16 + w2r16 + A8).
// VALU issue time (50us x 0.37 = 18.5us) already equals the VALU floor -> need waves.
// Cuts: single MFMA (D=16 AGPR); bias b1 baked into A k8 (B hi-lanes = bf16 1.0,
// C = 0) -> no cini; w2p/b2p in SGPRs (wave-uniform q via readfirstlane) consumed as
// SGPR fma operands under an exec-masked half-split -> no VGPR weight arrays; no
// explicit prefetch (8 waves of TLP replace ILP); one barrier/block (slab[128][33]).

#define QN 128
#define SN 8
#define HN 32
#define XROW 1024
#define BN_EPS 1e-3f

typedef short bf16x8 __attribute__((ext_vector_type(8)));
typedef float f32x16 __attribute__((ext_vector_type(16)));
typedef unsigned int u32;

#define WS_A_BYTES (QN * 64 * 16)                 // A[q][lane] 16B
#define WS_W_OFF   WS_A_BYTES
#define WS_W_BYTES (QN * 32 * 4)                  // w2p[q][half*16+r] (f32, D-reg order)
#define WS_B2_OFF  (WS_W_OFF + WS_W_BYTES)        // b2p[q]

static __device__ __forceinline__ u32 pkbf(float lo, float hi) {
    union { __hip_bfloat162 h2; u32 u; } c;
    c.h2 = __float22bfloat162_rn(float2{lo, hi});
    return c.u;
}
static __device__ __forceinline__ float rfl(float v) {
    return __uint_as_float(__builtin_amdgcn_readfirstlane(__float_as_uint(v)));
}

__global__ void divenc_prep(const float* __restrict__ W1, const float* __restrict__ b1,
                            const float* __restrict__ gamma_, const float* __restrict__ beta_,
                            const float* __restrict__ mmean, const float* __restrict__ mvar,
                            const float* __restrict__ W2, const float* __restrict__ b2,
                            unsigned char* __restrict__ ws)
{
    const int q = blockIdx.x;        // 0..127
    const int m = threadIdx.x;       // 0..63

    u32 d0 = 0, d1 = 0, d2 = 0, d3 = 0;
    if (m < 32) {                    // A[m][k0..7] = W1[q][k][m]
        d0 = pkbf(W1[(q*SN + 0)*HN + m], W1[(q*SN + 1)*HN + m]);
        d1 = pkbf(W1[(q*SN + 2)*HN + m], W1[(q*SN + 3)*HN + m]);
        d2 = pkbf(W1[(q*SN + 4)*HN + m], W1[(q*SN + 5)*HN + m]);
        d3 = pkbf(W1[(q*SN + 6)*HN + m], W1[(q*SN + 7)*HN + m]);
    } else {                         // A[m][k8] = b1[m] (bias; B k8 = 1.0), k9-15 = 0
        d0 = pkbf(b1[q*HN + (m - 32)], 0.f);
    }
    ((uint4*)ws)[q*64 + m] = uint4{d0, d1, d2, d3};

    float* wsW  = (float*)(ws + WS_W_OFF);
    float* wsB2 = (float*)(ws + WS_B2_OFF);
    if (m < 32) {                    // D-reg order: h = (r&3) + 8*(r>>2) + 4*half
        const int half = m >> 4, r = m & 15;
        const int h = (r & 3) + 8*(r >> 2) + 4*half;
        float inv = gamma_[q*HN+h] * rsqrtf(mvar[q*HN+h] + BN_EPS);
        wsW[q*32 + m] = inv * W2[q*HN + h];
    }
    if (m == 0) {
        float acc = b2[q];
        for (int h = 0; h < HN; ++h) {
            float inv = gamma_[q*HN+h] * rsqrtf(mvar[q*HN+h] + BN_EPS);
            acc += (beta_[q*HN+h] - mmean[q*HN+h]*inv) * W2[q*HN+h];
        }
        wsB2[q] = acc;
    }
}

__global__ __launch_bounds__(512, 6)
void divenc_mfma(const float* __restrict__ x, const unsigned char* __restrict__ ws,
                 float* __restrict__ out)
{
    const int tid  = threadIdx.x;
    const int lane = tid & 63;
    const int wv   = __builtin_amdgcn_readfirstlane(tid >> 6);  // wave-uniform 0..7
    const int bl   = lane & 31;
    const bool hi  = lane >= 32;
    const int b0   = blockIdx.x * 128;
    const int q0   = blockIdx.y * 32;

    const uint4* wsA  = (const uint4*)ws;
    const float* wsW  = (const float*)(ws + WS_W_OFF);
    const float* wsB2 = (const float*)(ws + WS_B2_OFF);

    __shared__ float slab[128][33];   // 16.9 KiB; stride 33 = conflict-free col writes

    #pragma unroll
    for (int qg = 0; qg < 4; ++qg) {
        const int q = q0 + qg*8 + wv;            // wave-uniform

        union { uint4 u; bf16x8 v; } A;
        A.u = wsA[q*64 + lane];

        // weights into SGPRs (uniform loads; readfirstlane pins uniformity)
        const float* wp = wsW + q*32;
        float sw[32];
        #pragma unroll
        for (int r = 0; r < 32; ++r) sw[r] = rfl(wp[r]);
        const float b2p = rfl(wsB2[q]);

        const float* xq = x + (size_t)(b0 + bl) * XROW + q * SN;

        #pragma unroll
        for (int sub = 0; sub < 4; ++sub) {
            const float* xp = xq + (size_t)(sub * 32) * XROW;
            float4 xa = *(const float4*)xp;       // hi lanes duplicate lo rows (same lines)
            float4 xc = *(const float4*)(xp + 4);

            const u32 k0 = pkbf(xa.x, xa.y), k1 = pkbf(xa.z, xa.w);
            const u32 k2 = pkbf(xc.x, xc.y), k3 = pkbf(xc.z, xc.w);

            union { uint4 u; bf16x8 v; } B;      // hi lanes: k8 = 1.0 (bias), k9-15 = 0
            B.u = uint4{ hi ? 0x00003F80u : k0,
                         hi ? 0u : k1,
                         hi ? 0u : k2,
                         hi ? 0u : k3 };

            f32x16 Z = {0.f,0.f,0.f,0.f,0.f,0.f,0.f,0.f,
                        0.f,0.f,0.f,0.f,0.f,0.f,0.f,0.f};
            f32x16 D = __builtin_amdgcn_mfma_f32_32x32x16_bf16(A.v, B.v, Z, 0, 0, 0);

            float u_[16];
            #pragma unroll
            for (int r = 0; r < 16; ++r) {
                float z = D[r];
                float e = __expf(fminf(z, 0.f)) - 1.f;   // z>0 -> e=0
                u_[r] = fmaxf(z, e);                     // exact ELU
            }
            float p = 0.f;
            if (!hi) {                                    // exec-masked: fma with SGPR src
                #pragma unroll
                for (int r = 0; r < 16; ++r) p = fmaf(u_[r], sw[r], p);
            } else {
                #pragma unroll
                for (int r = 0; r < 16; ++r) p = fmaf(u_[r], sw[16 + r], p);
            }
            p += __shfl_xor(p, 32);                       // combine h-halves (same b-col)
            if (!hi) slab[sub*32 + bl][qg*8 + wv] = p + b2p;
        }
    }

    __syncthreads();

    // dump 128 rows x 32 q; 512 threads x 32B (two float4)
    {
        const int row = tid >> 2;
        const int c0  = (tid & 3) * 8;
        float* orow = out + (size_t)(b0 + row) * QN + q0 + c0;
        float4 v0, v1;
        v0.x = slab[row][c0+0]; v0.y = slab[row][c0+1];
        v0.z = slab[row][c0+2]; v0.w = slab[row][c0+3];
        v1.x = slab[row][c0+4]; v1.y = slab[row][c0+5];
        v1.z = slab[row][c0+6]; v1.w = slab[row][c0+7];
        *(float4*)orow       = v0;
        *(float4*)(orow + 4) = v1;
    }
}

extern "C" void kernel_launch(void* const* d_in, const int* in_sizes, int n_in,
                              void* d_out, int out_size, void* d_ws, size_t ws_size,
                              hipStream_t stream) {
    const float* x      = (const float*)d_in[0];
    const float* W1     = (const float*)d_in[1];
    const float* b1     = (const float*)d_in[2];
    const float* gamma_ = (const float*)d_in[3];
    const float* beta_  = (const float*)d_in[4];
    const float* mmean  = (const float*)d_in[5];
    const float* mvar   = (const float*)d_in[6];
    const float* W2     = (const float*)d_in[7];
    const float* b2     = (const float*)d_in[8];
    float* out = (float*)d_out;
    unsigned char* ws = (unsigned char*)d_ws;

    const int Btot = in_sizes[0] / XROW;              // 32768

    divenc_prep<<<QN, 64, 0, stream>>>(W1, b1, gamma_, beta_, mmean, mvar, W2, b2, ws);
    divenc_mfma<<<dim3(Btot / 128, QN / 32), 512, 0, stream>>>(x, ws, out);
}

// Round 11
// 51.871 us; speedup vs baseline: 1.1871x; 1.0715x over previous
//
#include <hip/hip_runtime.h>
#include <hip/hip_bf16.h>

// DivEncLayer via MFMA, R11: clean sub-64-unified-reg kernel for 8 waves/SIMD.
// per (b,q): z = W1^T x + b1; out = sum_h w2p*elu(z) + b2p.  B=32768, Q=128, S=8, H=32.
//
// R10 -> R11: R10's SGPR/readfirstlane epilogue + exec-divergent halves added issue time
// that ate the residency gain. This round: R6's shape with single MFMA (D=16 AGPR),
// bias-in-A k8 (no cini), w2p in plain VGPRs (w2r[16], no divergence), no prefetch,
// launch_bounds(512,8) -> hard 64-reg unified budget -> 8 waves/SIMD (m69 cliff).
// ELU split: elu = E + R - 1, E=exp(min(z,0)), R=max(z,0); the -sum(w2p) folds into b2p
// at prep; p0/p1 dual accumulators halve the dependent fma chain.
// Unified tally: D16 + A4 + w2r16 + B4 + x8(transient) + b2p1 + ptrs/temps ~12 = ~61.

#define QN 128
#define SN 8
#define HN 32
#define XROW 1024
#define BN_EPS 1e-3f

typedef short bf16x8 __attribute__((ext_vector_type(8)));
typedef float f32x16 __attribute__((ext_vector_type(16)));
typedef unsigned int u32;

#define WS_A_BYTES (QN * 64 * 16)                 // A[q][lane] 16B
#define WS_W_OFF   WS_A_BYTES
#define WS_W_BYTES (QN * 32 * 4)                  // w2p[q][half*16+r] (f32, D-reg order)
#define WS_B2_OFF  (WS_W_OFF + WS_W_BYTES)        // b2p[q] (with -sum(w2p) folded)

static __device__ __forceinline__ u32 pkbf(float lo, float hi) {
    union { __hip_bfloat162 h2; u32 u; } c;
    c.h2 = __float22bfloat162_rn(float2{lo, hi});
    return c.u;
}

__global__ void divenc_prep(const float* __restrict__ W1, const float* __restrict__ b1,
                            const float* __restrict__ gamma_, const float* __restrict__ beta_,
                            const float* __restrict__ mmean, const float* __restrict__ mvar,
                            const float* __restrict__ W2, const float* __restrict__ b2,
                            unsigned char* __restrict__ ws)
{
    const int q = blockIdx.x;        // 0..127
    const int m = threadIdx.x;       // 0..63

    u32 d0 = 0, d1 = 0, d2 = 0, d3 = 0;
    if (m < 32) {                    // A[m][k0..7] = W1[q][k][m]
        d0 = pkbf(W1[(q*SN + 0)*HN + m], W1[(q*SN + 1)*HN + m]);
        d1 = pkbf(W1[(q*SN + 2)*HN + m], W1[(q*SN + 3)*HN + m]);
        d2 = pkbf(W1[(q*SN + 4)*HN + m], W1[(q*SN + 5)*HN + m]);
        d3 = pkbf(W1[(q*SN + 6)*HN + m], W1[(q*SN + 7)*HN + m]);
    } else {                         // A[m][k8] = b1[m] (bias; B k8 = 1.0), k9-15 = 0
        d0 = pkbf(b1[q*HN + (m - 32)], 0.f);
    }
    ((uint4*)ws)[q*64 + m] = uint4{d0, d1, d2, d3};

    float* wsW  = (float*)(ws + WS_W_OFF);
    float* wsB2 = (float*)(ws + WS_B2_OFF);
    if (m < 32) {                    // D-reg order: h = (r&3) + 8*(r>>2) + 4*half
        const int half = m >> 4, r = m & 15;
        const int h = (r & 3) + 8*(r >> 2) + 4*half;
        float inv = gamma_[q*HN+h] * rsqrtf(mvar[q*HN+h] + BN_EPS);
        wsW[q*32 + m] = inv * W2[q*HN + h];
    }
    if (m == 0) {
        float acc = b2[q];
        for (int h = 0; h < HN; ++h) {
            float inv = gamma_[q*HN+h] * rsqrtf(mvar[q*HN+h] + BN_EPS);
            float w2p = inv * W2[q*HN + h];
            acc += (beta_[q*HN+h] - mmean[q*HN+h]*inv) * W2[q*HN+h] - w2p;  // fold -sum(w2p)
        }
        wsB2[q] = acc;
    }
}

__global__ __launch_bounds__(512, 8)
void divenc_mfma(const float* __restrict__ x, const unsigned char* __restrict__ ws,
                 float* __restrict__ out)
{
    const int tid  = threadIdx.x;
    const int lane = tid & 63;
    const int wv   = tid >> 6;       // 0..7
    const int half = lane >> 5;
    const int bl   = lane & 31;
    const bool hi  = lane >= 32;
    const int b0   = blockIdx.x * 128;
    const int q0   = blockIdx.y * 32;

    __shared__ float slab[128][33];  // 16.9 KiB; stride 33 = conflict-free col writes

    const uint4* wsA  = (const uint4*)ws + (size_t)(q0 + wv) * 64;
    const float* wsW  = (const float*)(ws + WS_W_OFF) + (q0 + wv) * 32 + half * 16;
    const float* wsB2 = (const float*)(ws + WS_B2_OFF) + (q0 + wv);
    const float* xq   = x + (size_t)(b0 + bl) * XROW + (q0 + wv) * SN;

    #pragma unroll 1
    for (int qg = 0; qg < 4; ++qg) {
        union { uint4 u; bf16x8 v; } A;
        A.u = wsA[lane];

        float w2r[16];
        #pragma unroll
        for (int r = 0; r < 16; ++r) w2r[r] = wsW[r];
        const float b2p = wsB2[0];

        #pragma unroll
        for (int sub = 0; sub < 4; ++sub) {
            const float* xp = xq + (size_t)(sub * 32) * XROW;
            const float4 xa = *(const float4*)xp;      // hi lanes dup lo rows (same lines)
            const float4 xc = *(const float4*)(xp + 4);

            union { uint4 u; bf16x8 v; } B;            // hi: k8 = bf16(1.0), k9-15 = 0
            B.u = uint4{ hi ? 0x00003F80u : pkbf(xa.x, xa.y),
                         hi ? 0u : pkbf(xa.z, xa.w),
                         hi ? 0u : pkbf(xc.x, xc.y),
                         hi ? 0u : pkbf(xc.z, xc.w) };

            const f32x16 Z = {0.f,0.f,0.f,0.f,0.f,0.f,0.f,0.f,
                              0.f,0.f,0.f,0.f,0.f,0.f,0.f,0.f};
            f32x16 D = __builtin_amdgcn_mfma_f32_32x32x16_bf16(A.v, B.v, Z, 0, 0, 0);

            float p0 = 0.f, p1 = 0.f;                  // elu = E + R - 1 (the -1 is in b2p)
            #pragma unroll
            for (int r = 0; r < 16; ++r) {
                const float z = D[r];
                const float E = __expf(fminf(z, 0.f)); // z>0 -> 1
                const float R = fmaxf(z, 0.f);
                p0 = fmaf(E, w2r[r], p0);
                p1 = fmaf(R, w2r[r], p1);
            }
            float p = p0 + p1;
            p += __shfl_xor(p, 32);                    // combine h-halves (same b-col)
            if (!hi) slab[sub*32 + bl][qg*8 + wv] = p + b2p;
        }

        wsA  += 8 * 64;
        wsW  += 8 * 32;
        wsB2 += 8;
        xq   += 8 * SN;
    }

    __syncthreads();

    // dump 128 rows x 32 q; 512 threads x 32B (two float4) -> full 128B lines
    {
        const int row = tid >> 2;
        const int c0  = (tid & 3) * 8;
        float* orow = out + (size_t)(b0 + row) * QN + q0 + c0;
        float4 v0, v1;
        v0.x = slab[row][c0+0]; v0.y = slab[row][c0+1];
        v0.z = slab[row][c0+2]; v0.w = slab[row][c0+3];
        v1.x = slab[row][c0+4]; v1.y = slab[row][c0+5];
        v1.z = slab[row][c0+6]; v1.w = slab[row][c0+7];
        *(float4*)orow       = v0;
        *(float4*)(orow + 4) = v1;
    }
}

extern "C" void kernel_launch(void* const* d_in, const int* in_sizes, int n_in,
                              void* d_out, int out_size, void* d_ws, size_t ws_size,
                              hipStream_t stream) {
    const float* x      = (const float*)d_in[0];
    const float* W1     = (const float*)d_in[1];
    const float* b1     = (const float*)d_in[2];
    const float* gamma_ = (const float*)d_in[3];
    const float* beta_  = (const float*)d_in[4];
    const float* mmean  = (const float*)d_in[5];
    const float* mvar   = (const float*)d_in[6];
    const float* W2     = (const float*)d_in[7];
    const float* b2     = (const float*)d_in[8];
    float* out = (float*)d_out;
    unsigned char* ws = (unsigned char*)d_ws;

    const int Btot = in_sizes[0] / XROW;              // 32768

    divenc_prep<<<QN, 64, 0, stream>>>(W1, b1, gamma_, beta_, mmean, mvar, W2, b2, ws);
    divenc_mfma<<<dim3(Btot / 128, QN / 32), 512, 0, stream>>>(x, ws, out);
}